// Round 11
// baseline (416.418 us; speedup 1.0000x reference)
//
#include <hip/hip_runtime.h>
#include <math.h>

#define N_N 8000
#define N_E 12000
#define N_A 48000
#define N_B 64
#define N_H 64
#define N_DH 4096

typedef _Float16 h16;
typedef __attribute__((ext_vector_type(8))) _Float16 h16x8;
typedef __attribute__((ext_vector_type(4))) float f32x4;

__device__ __forceinline__ float atomAddF(float* p, float v) {
  return __hip_atomic_fetch_add(p, v, __ATOMIC_RELAXED, __HIP_MEMORY_SCOPE_AGENT);
}
__device__ __forceinline__ float sigm(float x) { return 1.f / (1.f + expf(-x)); }

// ---------------- mega setup kernel ----------------
// ranges: proj | ef-feat | wang | prep | bounds | zero(amsg0,nacc0,qstar-block)
#define SB_PROJ 2000
#define SB_FEAT (SB_PROJ + 47)
#define SB_WANG (SB_FEAT + 188)
#define SB_PREP (SB_WANG + 704)
#define SB_BND  (SB_PREP + 32)
#define SB_END  (SB_BND + 1330)
#define PREP_B0 32768                 // w3t   [256][128]
#define PREP_B1 (PREP_B0 + 69632)     // ttA   [1088][64]
#define PREP_B2 (PREP_B1 + 69632)     // ttB   [1088][64]
#define PREP_B3 (PREP_B2 + 4096)      // wtAU  [64][64]
#define PREP_B4 (PREP_B3 + 4096)      // wtBU  [64][64]

__global__ __launch_bounds__(256) void k_setup(
    const float* __restrict__ na, const float* __restrict__ projW,
    const float* __restrict__ projb, const float* __restrict__ ea,
    const float* __restrict__ el, const float* __restrict__ ang,
    const int* __restrict__ gid,
    const float* __restrict__ gWih, const float* __restrict__ gWhh,
    const float* __restrict__ efW, const float* __restrict__ efb,
    const float* __restrict__ bondW, const float* __restrict__ bondb,
    const float* __restrict__ auW, const float* __restrict__ buW,
    float* __restrict__ x0, float* __restrict__ ef, float* __restrict__ wang,
    int* __restrict__ gstart, int* __restrict__ gend,
    h16* __restrict__ W3t, h16* __restrict__ ttA, h16* __restrict__ ttB,
    h16* __restrict__ wtAU, h16* __restrict__ wtBU,
    float4* __restrict__ amsg0_4, float4* __restrict__ nacc0_4,
    float4* __restrict__ qz_4) {
  int bx = blockIdx.x, tid = threadIdx.x;
  if (bx < SB_PROJ) {
    int wid = bx * 4 + (tid >> 6);
    int lane = tid & 63;
    if (wid < N_N) {
      const float* row = na + (size_t)wid * 110;
      float acc = projb[lane];
      for (int k = 0; k < 110; ++k) acc = fmaf(row[k], projW[k * 64 + lane], acc);
      x0[(size_t)wid * 64 + lane] = fmaxf(acc, 0.f);
    }
  } else if (bx < SB_FEAT) {
    int e = (bx - SB_PROJ) * 256 + tid;
    if (e < N_E) {
      const float g2 = (7.f / 4.f) * (7.f / 4.f);
      float x = el[e];
#pragma unroll
      for (int j = 0; j < 8; ++j) ef[e * 16 + j] = ea[e * 8 + j];
#pragma unroll
      for (int j = 0; j < 8; ++j) {
        float d = x - j * (4.f / 7.f);
        ef[e * 16 + 8 + j] = expf(-g2 * d * d);
      }
    }
  } else if (bx < SB_WANG) {
    int a = (bx - SB_FEAT) * 256 + tid;
    if (a < N_A) {
      const float PIf = 3.14159265358979323846f;
      const float g1 = (7.f / PIf) * (7.f / PIf);
      float x = ang[a];
#pragma unroll
      for (int j = 0; j < 8; ++j) {
        float d = x - j * (PIf / 7.f);
        wang[(size_t)a * 8 + j] = expf(-g1 * d * d);
      }
    }
  } else if (bx < SB_PREP) {
    int i = (bx - SB_WANG) * 256 + tid;
    if (i < PREP_B0) {
      int col = i >> 7, k = i & 127;
      int grp = col >> 6, u = col & 63;
      float v;
      if (grp == 0) v = (k < 64) ? gWih[u * 64 + k] : gWhh[u * 64 + k - 64];
      else if (grp == 1) v = (k < 64) ? gWih[(64 + u) * 64 + k] : gWhh[(64 + u) * 64 + k - 64];
      else if (grp == 2) v = (k < 64) ? gWih[(128 + u) * 64 + k] : 0.f;
      else v = (k < 64) ? 0.f : gWhh[(128 + u) * 64 + k - 64];
      W3t[i] = (h16)v;
    } else if (i < PREP_B1) {
      int j = i - PREP_B0;
      int n = j >> 6, i2 = j & 63;
      int k = n >> 6, o = n & 63;
      float val = (k < 16) ? efW[(size_t)k * 4096 + i2 * 64 + o] : efb[i2 * 64 + o];
      ttA[j] = (h16)val;
    } else if (i < PREP_B2) {
      int j = i - PREP_B1;
      int n = j >> 6, i2 = j & 63;
      int k = n >> 6, o = n & 63;
      float val = (k < 16) ? bondW[(size_t)k * 4096 + i2 * 64 + o] : bondb[i2 * 64 + o];
      ttB[j] = (h16)val;
    } else if (i < PREP_B3) {
      int j = i - PREP_B2;
      int o = j >> 6, i2 = j & 63;
      wtAU[j] = (h16)auW[i2 * 64 + o];
    } else if (i < PREP_B4) {
      int j = i - PREP_B3;
      int o = j >> 6, i2 = j & 63;
      wtBU[j] = (h16)buW[i2 * 64 + o];
    }
  } else if (bx < SB_BND) {
    int n = (bx - SB_PREP) * 256 + tid;
    if (n < N_N) {
      int g = gid[n];
      if (n == 0 || gid[n - 1] != g) gstart[g] = n;
      if (n == N_N - 1 || gid[n + 1] != g) gend[g] = n + 1;
    }
  } else if (bx < SB_END) {
    int i = (bx - SB_BND) * 256 + tid;
    float4 z = (float4){0.f, 0.f, 0.f, 0.f};
    if (i < 192000) amsg0_4[i] = z;
    else if (i < 320000) nacc0_4[i - 192000] = z;
    else if (i < 340480) qz_4[i - 320000] = z;
  }
}

// ---------------- per-edge P8/Q precompute (16 edges/wave, 64/block) ----------------
// ha[e] = relu(x[esrc[e]]@auW+aub) (inline MFMA, swizzled-LDS relayout)
// P8[e][kk][o] = ha[e] @ ttA[kk*64+o]           kk = 0..7   (angle-rbf slices)
// Q[e][o]     = sum_{j<8} lenrbf[e][j]*(ha@ttA[(8+j)*64+o]) + ha@ttA[16*64+o]
// blockIdx.y: 0: P8 kk0-3 | 1: P8 kk4-7 | 2: Q o0-31 | 3: Q o32-63
__global__ __launch_bounds__(256) void k_edgeP(
    const float* __restrict__ xcur, const int* __restrict__ esrc,
    const h16* __restrict__ wtAU, const float* __restrict__ aub,
    const h16* __restrict__ ttA, const float* __restrict__ ef,
    h16* __restrict__ P8, float* __restrict__ Q) {
  __shared__ h16 haT[4][1024];      // per-wave 16x64 fp16 tile (XOR-swizzled)
  __shared__ float f_lds[64 * 9];
  int tid = threadIdx.x, wave = tid >> 6, lane = tid & 63;
  int l15 = lane & 15, lq = lane >> 4;
  int oc = blockIdx.y;
  int base = blockIdx.x * 64;
  if (oc >= 2) {
    for (int e2 = tid; e2 < 64 * 8; e2 += 256) {
      int il = e2 >> 3, k = e2 & 7;
      int g = base + il;
      if (g >= N_E) g = N_E - 1;
      f_lds[il * 9 + k] = ef[(size_t)g * 16 + 8 + k];
    }
    __syncthreads();
  }
  int ibl = wave * 16, ib0 = base + ibl;
  h16* myT = haT[wave];

  // inline MLP (full 64 outs, 16 edges)
  {
    h16x8 xafr[2];
    {
      int item = ib0 + l15;
      if (item >= N_E) item = N_E - 1;
      const float* vp = xcur + (size_t)esrc[item] * 64;
#pragma unroll
      for (int ks = 0; ks < 2; ++ks) {
        const float4* p = (const float4*)(vp + ks * 32 + 8 * lq);
        float4 v0 = p[0], v1 = p[1];
        h16x8 a;
        a[0] = (h16)v0.x; a[1] = (h16)v0.y; a[2] = (h16)v0.z; a[3] = (h16)v0.w;
        a[4] = (h16)v1.x; a[5] = (h16)v1.y; a[6] = (h16)v1.z; a[7] = (h16)v1.w;
        xafr[ks] = a;
      }
    }
    f32x4 aU[4];
#pragma unroll
    for (int nt = 0; nt < 4; ++nt) aU[nt] = (f32x4){0.f, 0.f, 0.f, 0.f};
#pragma unroll
    for (int nt = 0; nt < 4; ++nt)
#pragma unroll
      for (int ks = 0; ks < 2; ++ks) {
        h16x8 b = *(const h16x8*)(wtAU + (size_t)(nt * 16 + l15) * 64 + ks * 32 + 8 * lq);
        aU[nt] = __builtin_amdgcn_mfma_f32_16x16x32_f16(xafr[ks], b, aU[nt], 0, 0, 0);
      }
#pragma unroll
    for (int nt = 0; nt < 4; ++nt) {
      int o = nt * 16 + l15;
      float bo = aub[o];
#pragma unroll
      for (int r = 0; r < 4; ++r) {
        int row = lq * 4 + r;
        float val = fmaxf(aU[nt][r] + bo, 0.f);
        int idx = (((row * 64 + o) << 1) ^ ((row & 7) << 4)) >> 1;
        myT[idx] = (h16)val;
      }
    }
  }
  h16x8 afr[2];
#pragma unroll
  for (int ks = 0; ks < 2; ++ks) {
    int row = l15;
    int byte = ((row * 64 + ks * 32 + 8 * lq) << 1) ^ ((row & 7) << 4);
    afr[ks] = *(const h16x8*)((const char*)myT + byte);
  }

  if (oc < 2) {
#pragma unroll
    for (int kk = oc * 4; kk < oc * 4 + 4; ++kk) {
      f32x4 acc[4];
#pragma unroll
      for (int nt = 0; nt < 4; ++nt) acc[nt] = (f32x4){0.f, 0.f, 0.f, 0.f};
#pragma unroll
      for (int nt = 0; nt < 4; ++nt)
#pragma unroll
        for (int ks = 0; ks < 2; ++ks) {
          h16x8 b = *(const h16x8*)(ttA + (size_t)(kk * 64 + nt * 16 + l15) * 64 +
                                    ks * 32 + 8 * lq);
          acc[nt] = __builtin_amdgcn_mfma_f32_16x16x32_f16(afr[ks], b, acc[nt], 0, 0, 0);
        }
#pragma unroll
      for (int r = 0; r < 4; ++r) {
        int e = ib0 + lq * 4 + r;
        if (e < N_E) {
#pragma unroll
          for (int nt = 0; nt < 4; ++nt)
            P8[((size_t)e * 8 + kk) * 64 + nt * 16 + l15] = (h16)acc[nt][r];
        }
      }
    }
  } else {
    int no = oc - 2;
    f32x4 qacc[2];
    qacc[0] = (f32x4){0.f, 0.f, 0.f, 0.f};
    qacc[1] = (f32x4){0.f, 0.f, 0.f, 0.f};
    for (int kk = 8; kk < 16; ++kk) {
      h16 fs = (h16)f_lds[(ibl + l15) * 9 + (kk - 8)];
      h16x8 a2[2];
      a2[0] = afr[0] * fs;
      a2[1] = afr[1] * fs;
#pragma unroll
      for (int nt = 0; nt < 2; ++nt)
#pragma unroll
        for (int ks = 0; ks < 2; ++ks) {
          h16x8 b = *(const h16x8*)(ttA + (size_t)(kk * 64 + (no * 2 + nt) * 16 + l15) * 64 +
                                    ks * 32 + 8 * lq);
          qacc[nt] = __builtin_amdgcn_mfma_f32_16x16x32_f16(a2[ks], b, qacc[nt], 0, 0, 0);
        }
    }
#pragma unroll
    for (int nt = 0; nt < 2; ++nt)
#pragma unroll
      for (int ks = 0; ks < 2; ++ks) {
        h16x8 b = *(const h16x8*)(ttA + (size_t)(16 * 64 + (no * 2 + nt) * 16 + l15) * 64 +
                                  ks * 32 + 8 * lq);
        qacc[nt] = __builtin_amdgcn_mfma_f32_16x16x32_f16(afr[ks], b, qacc[nt], 0, 0, 0);
      }
#pragma unroll
    for (int r = 0; r < 4; ++r) {
      int e = ib0 + lq * 4 + r;
      if (e < N_E) {
#pragma unroll
        for (int nt = 0; nt < 2; ++nt)
          Q[(size_t)e * 64 + (no * 2 + nt) * 16 + l15] = qacc[nt][r];
      }
    }
  }
}

// ---------------- per-angle gather + scatter (wang table, no expf) ----------------
__global__ __launch_bounds__(256) void k_angle(
    const float* __restrict__ wang, const int* __restrict__ asrc,
    const int* __restrict__ adst, const h16* __restrict__ P8,
    const float* __restrict__ Q, float* __restrict__ amsg) {
  int w = (blockIdx.x * blockDim.x + threadIdx.x) >> 6;
  int lane = threadIdx.x & 63;
  if (w >= N_A) return;
  int e = asrc[w], d = adst[w];
  float acc = Q[(size_t)e * 64 + lane];
  const h16* p = P8 + (size_t)e * 512;
  const float4* wp = (const float4*)(wang + (size_t)w * 8);
  float4 w0 = wp[0], w1 = wp[1];
  acc = fmaf(w0.x, (float)p[0 * 64 + lane], acc);
  acc = fmaf(w0.y, (float)p[1 * 64 + lane], acc);
  acc = fmaf(w0.z, (float)p[2 * 64 + lane], acc);
  acc = fmaf(w0.w, (float)p[3 * 64 + lane], acc);
  acc = fmaf(w1.x, (float)p[4 * 64 + lane], acc);
  acc = fmaf(w1.y, (float)p[5 * 64 + lane], acc);
  acc = fmaf(w1.z, (float)p[6 * 64 + lane], acc);
  acc = fmaf(w1.w, (float)p[7 * 64 + lane], acc);
  atomAddF(amsg + (size_t)d * 64 + lane, acc);
}

// ---------------- bond (16 edges/wave, 64/block): inline MLP(+amsg) + contraction + scatter
// blockIdx.y = o-quarter (16 outs). Zeroes zbuf via y==0 blocks.
__global__ __launch_bounds__(256) void k_bond(
    const float* __restrict__ xcur, const int* __restrict__ esrc,
    const h16* __restrict__ wtBU, const float* __restrict__ bub,
    const float* __restrict__ amsg_in, const float* __restrict__ ef,
    const h16* __restrict__ ttB, const int* __restrict__ edst,
    float* __restrict__ nacc, float4* __restrict__ zbuf, int zcount4) {
  if (blockIdx.y == 0) {
    int stride = gridDim.x * 256;
    for (int i = blockIdx.x * 256 + threadIdx.x; i < zcount4; i += stride)
      zbuf[i] = (float4){0.f, 0.f, 0.f, 0.f};
  }
  __shared__ h16 haT[4][1024];
  __shared__ float f_lds[64 * 17];
  __shared__ int dst_lds[64];
  int tid = threadIdx.x;
  int base = blockIdx.x * 64;
  int oc = blockIdx.y;
  for (int e2 = tid; e2 < 64 * 16; e2 += 256) {
    int il = e2 >> 4, k = e2 & 15;
    int g = base + il;
    if (g >= N_E) g = N_E - 1;
    f_lds[il * 17 + k] = ef[(size_t)g * 16 + k];
  }
  if (tid < 64) {
    int g = base + tid;
    if (g >= N_E) g = N_E - 1;
    dst_lds[tid] = edst[g];
  }
  __syncthreads();

  int wave = tid >> 6, lane = tid & 63;
  int l15 = lane & 15, lq = lane >> 4;
  int ibl = wave * 16, ib0 = base + ibl;
  h16* myT = haT[wave];

  {
    h16x8 xafr[2];
    {
      int item = ib0 + l15;
      if (item >= N_E) item = N_E - 1;
      const float* vp = xcur + (size_t)esrc[item] * 64;
#pragma unroll
      for (int ks = 0; ks < 2; ++ks) {
        const float4* p = (const float4*)(vp + ks * 32 + 8 * lq);
        float4 v0 = p[0], v1 = p[1];
        h16x8 a;
        a[0] = (h16)v0.x; a[1] = (h16)v0.y; a[2] = (h16)v0.z; a[3] = (h16)v0.w;
        a[4] = (h16)v1.x; a[5] = (h16)v1.y; a[6] = (h16)v1.z; a[7] = (h16)v1.w;
        xafr[ks] = a;
      }
    }
    f32x4 aU[4];
#pragma unroll
    for (int nt = 0; nt < 4; ++nt) aU[nt] = (f32x4){0.f, 0.f, 0.f, 0.f};
#pragma unroll
    for (int nt = 0; nt < 4; ++nt)
#pragma unroll
      for (int ks = 0; ks < 2; ++ks) {
        h16x8 b = *(const h16x8*)(wtBU + (size_t)(nt * 16 + l15) * 64 + ks * 32 + 8 * lq);
        aU[nt] = __builtin_amdgcn_mfma_f32_16x16x32_f16(xafr[ks], b, aU[nt], 0, 0, 0);
      }
#pragma unroll
    for (int nt = 0; nt < 4; ++nt) {
      int o = nt * 16 + l15;
      float bo = bub[o];
#pragma unroll
      for (int r = 0; r < 4; ++r) {
        int row = lq * 4 + r;
        int item = ib0 + row;
        if (item >= N_E) item = N_E - 1;
        float val = fmaxf(aU[nt][r] + bo, 0.f) + amsg_in[(size_t)item * 64 + o];
        int idx = (((row * 64 + o) << 1) ^ ((row & 7) << 4)) >> 1;
        myT[idx] = (h16)val;
      }
    }
  }
  h16x8 afr[2];
#pragma unroll
  for (int ks = 0; ks < 2; ++ks) {
    int row = l15;
    int byte = ((row * 64 + ks * 32 + 8 * lq) << 1) ^ ((row & 7) << 4);
    afr[ks] = *(const h16x8*)((const char*)myT + byte);
  }

  f32x4 acc = (f32x4){0.f, 0.f, 0.f, 0.f};
  for (int kk = 0; kk < 16; ++kk) {
    h16x8 bfr[2];
#pragma unroll
    for (int ks = 0; ks < 2; ++ks)
      bfr[ks] = *(const h16x8*)(ttB + (size_t)(kk * 64 + oc * 16 + l15) * 64 + ks * 32 + 8 * lq);
    h16 fs = (h16)f_lds[(ibl + l15) * 17 + kk];
    h16x8 a2[2];
    a2[0] = afr[0] * fs;
    a2[1] = afr[1] * fs;
#pragma unroll
    for (int ks = 0; ks < 2; ++ks)
      acc = __builtin_amdgcn_mfma_f32_16x16x32_f16(a2[ks], bfr[ks], acc, 0, 0, 0);
  }
  {
    h16x8 bfr[2];
#pragma unroll
    for (int ks = 0; ks < 2; ++ks)
      bfr[ks] = *(const h16x8*)(ttB + (size_t)(16 * 64 + oc * 16 + l15) * 64 + ks * 32 + 8 * lq);
#pragma unroll
    for (int ks = 0; ks < 2; ++ks)
      acc = __builtin_amdgcn_mfma_f32_16x16x32_f16(afr[ks], bfr[ks], acc, 0, 0, 0);
  }
#pragma unroll
  for (int r = 0; r < 4; ++r) {
    int il = ibl + lq * 4 + r;
    int item = base + il;
    if (item < N_E)
      atomAddF(nacc + (size_t)dst_lds[il] * 64 + oc * 16 + l15, acc[r]);
  }
}

// ---------------- MFMA GRU (32 nodes/block, 2 waves -> 250 blocks) ----------------
__global__ __launch_bounds__(128) void k_gru2(
    const float* __restrict__ nacc, const float* __restrict__ gnnb,
    const float* __restrict__ h, const h16* __restrict__ W3t,
    const float* __restrict__ gbih, const float* __restrict__ gbhh,
    float* __restrict__ hout, const float* __restrict__ x0,
    float* __restrict__ agg, int wagg, float4* __restrict__ zbuf, int zcount4) {
  if (zbuf) {
    int stride = gridDim.x * 128;
    for (int i = blockIdx.x * 128 + threadIdx.x; i < zcount4; i += stride)
      zbuf[i] = (float4){0.f, 0.f, 0.f, 0.f};
  }
  int tid = threadIdx.x, wave = tid >> 6, lane = tid & 63;
  int l15 = lane & 15, lq = lane >> 4;
  int ib0 = blockIdx.x * 32 + wave * 16;
  int nodeA = ib0 + l15;
  if (nodeA >= N_N) nodeA = N_N - 1;

  h16x8 afr[4];
#pragma unroll
  for (int ks = 0; ks < 2; ++ks) {
    const float4* p = (const float4*)(nacc + (size_t)nodeA * 64 + ks * 32 + 8 * lq);
    const float4* gp = (const float4*)(gnnb + ks * 32 + 8 * lq);
    float4 v0 = p[0], v1 = p[1], g0 = gp[0], g1 = gp[1];
    h16x8 a;
    a[0] = (h16)fmaxf(v0.x + g0.x, 0.f); a[1] = (h16)fmaxf(v0.y + g0.y, 0.f);
    a[2] = (h16)fmaxf(v0.z + g0.z, 0.f); a[3] = (h16)fmaxf(v0.w + g0.w, 0.f);
    a[4] = (h16)fmaxf(v1.x + g1.x, 0.f); a[5] = (h16)fmaxf(v1.y + g1.y, 0.f);
    a[6] = (h16)fmaxf(v1.z + g1.z, 0.f); a[7] = (h16)fmaxf(v1.w + g1.w, 0.f);
    afr[ks] = a;
  }
#pragma unroll
  for (int ks = 0; ks < 2; ++ks) {
    const float4* p = (const float4*)(h + (size_t)nodeA * 64 + ks * 32 + 8 * lq);
    float4 v0 = p[0], v1 = p[1];
    h16x8 a;
    a[0] = (h16)v0.x; a[1] = (h16)v0.y; a[2] = (h16)v0.z; a[3] = (h16)v0.w;
    a[4] = (h16)v1.x; a[5] = (h16)v1.y; a[6] = (h16)v1.z; a[7] = (h16)v1.w;
    afr[2 + ks] = a;
  }

  f32x4 acc[16];
#pragma unroll
  for (int nt = 0; nt < 16; ++nt) acc[nt] = (f32x4){0.f, 0.f, 0.f, 0.f};
#pragma unroll
  for (int nt = 0; nt < 16; ++nt) {
#pragma unroll
    for (int ks = 0; ks < 4; ++ks) {
      if (nt >= 8 && nt < 12 && ks >= 2) continue;
      if (nt >= 12 && ks < 2) continue;
      h16x8 b = *(const h16x8*)(W3t + (size_t)(nt * 16 + l15) * 128 + ks * 32 + 8 * lq);
      acc[nt] = __builtin_amdgcn_mfma_f32_16x16x32_f16(afr[ks], b, acc[nt], 0, 0, 0);
    }
  }

#pragma unroll
  for (int nt0 = 0; nt0 < 4; ++nt0) {
    int u = nt0 * 16 + l15;
    float br = gbih[u] + gbhh[u];
    float bz = gbih[64 + u] + gbhh[64 + u];
    float bin_ = gbih[128 + u];
    float bhn = gbhh[128 + u];
#pragma unroll
    for (int r = 0; r < 4; ++r) {
      int node = ib0 + lq * 4 + r;
      if (node < N_N) {
        float rr = sigm(acc[nt0][r] + br);
        float zz = sigm(acc[nt0 + 4][r] + bz);
        float nn = tanhf(acc[nt0 + 8][r] + bin_ + rr * (acc[nt0 + 12][r] + bhn));
        float hv = h[(size_t)node * 64 + u];
        float val = (1.f - zz) * nn + zz * hv;
        hout[(size_t)node * 64 + u] = val;
        if (wagg) {
          agg[(size_t)node * 128 + u] = val;
          agg[(size_t)node * 128 + 64 + u] = x0[(size_t)node * 64 + u];
        }
      }
    }
  }
}

// ---------------- Set2Set (split kernels — measured-good) ----------------

__global__ __launch_bounds__(256) void k_lstm2(
    const float* __restrict__ x, int xdim,
    const float* __restrict__ hin, const float* __restrict__ cin,
    const float* __restrict__ Wih, const float* __restrict__ Whh,
    const float* __restrict__ bih, const float* __restrict__ bhh,
    float* __restrict__ hout, float* __restrict__ cout) {
  int w = (blockIdx.x * blockDim.x + threadIdx.x) >> 6;
  int lane = threadIdx.x & 63;
  if (w >= N_B * 128) return;
  int b = w >> 7, u = w & 127;
  float a0 = 0.f, a1 = 0.f, a2 = 0.f, a3 = 0.f;
  const float* xr = x + (size_t)b * xdim;
  for (int k = lane; k < xdim; k += 64) {
    float xv = xr[k];
    a0 = fmaf(xv, Wih[(size_t)u * xdim + k], a0);
    a1 = fmaf(xv, Wih[(size_t)(128 + u) * xdim + k], a1);
    a2 = fmaf(xv, Wih[(size_t)(256 + u) * xdim + k], a2);
    a3 = fmaf(xv, Wih[(size_t)(384 + u) * xdim + k], a3);
  }
  const float* hr = hin + (size_t)b * 128;
#pragma unroll
  for (int k0 = 0; k0 < 128; k0 += 64) {
    int k = k0 + lane;
    float hv = hr[k];
    a0 = fmaf(hv, Whh[(size_t)u * 128 + k], a0);
    a1 = fmaf(hv, Whh[(size_t)(128 + u) * 128 + k], a1);
    a2 = fmaf(hv, Whh[(size_t)(256 + u) * 128 + k], a2);
    a3 = fmaf(hv, Whh[(size_t)(384 + u) * 128 + k], a3);
  }
#pragma unroll
  for (int mm = 1; mm < 64; mm <<= 1) {
    a0 += __shfl_xor(a0, mm);
    a1 += __shfl_xor(a1, mm);
    a2 += __shfl_xor(a2, mm);
    a3 += __shfl_xor(a3, mm);
  }
  if (lane == 0) {
    float gi = a0 + bih[u] + bhh[u];
    float gf = a1 + bih[128 + u] + bhh[128 + u];
    float gg = a2 + bih[256 + u] + bhh[256 + u];
    float go = a3 + bih[384 + u] + bhh[384 + u];
    float c2 = sigm(gf) * cin[(size_t)b * 128 + u] + sigm(gi) * tanhf(gg);
    hout[(size_t)b * 128 + u] = sigm(go) * tanhf(c2);
    cout[(size_t)b * 128 + u] = c2;
  }
}

__global__ __launch_bounds__(256) void k_pool2(
    const float* __restrict__ agg, const int* __restrict__ gstart,
    const int* __restrict__ gend, const float* __restrict__ q,
    float* __restrict__ q_star) {
  int g = blockIdx.x;
  int s = gstart[g], t = gend[g];
  int cnt = t - s;
  if (cnt < 0) cnt = 0;
  if (cnt > 1024) cnt = 1024;
  __shared__ float ew[1024];
  __shared__ float red[8];
  __shared__ float comb[256];
  int tid = threadIdx.x, wave = tid >> 6, lane = tid & 63;
  float qa = q[g * 128 + lane], qb = q[g * 128 + 64 + lane];
  for (int i = wave; i < cnt; i += 4) {
    int n = s + i;
    float a = agg[(size_t)n * 128 + lane] * qa + agg[(size_t)n * 128 + 64 + lane] * qb;
#pragma unroll
    for (int mm = 1; mm < 64; mm <<= 1) a += __shfl_xor(a, mm);
    if (lane == 0) ew[i] = a;
  }
  __syncthreads();
  float mx = -INFINITY;
  for (int i = tid; i < cnt; i += 256) mx = fmaxf(mx, ew[i]);
#pragma unroll
  for (int mm = 1; mm < 64; mm <<= 1) mx = fmaxf(mx, __shfl_xor(mx, mm));
  if (lane == 0) red[wave] = mx;
  __syncthreads();
  mx = fmaxf(fmaxf(red[0], red[1]), fmaxf(red[2], red[3]));
  float sm = 0.f;
  for (int i = tid; i < cnt; i += 256) sm += expf(ew[i] - mx);
#pragma unroll
  for (int mm = 1; mm < 64; mm <<= 1) sm += __shfl_xor(sm, mm);
  if (lane == 0) red[4 + wave] = sm;
  __syncthreads();
  sm = red[4] + red[5] + red[6] + red[7];
  float inv = (sm > 0.f) ? 1.f / sm : 0.f;
  __syncthreads();
  for (int i = tid; i < cnt; i += 256) ew[i] = expf(ew[i] - mx) * inv;
  __syncthreads();
  int d = tid & 127, half = tid >> 7;
  float acc = 0.f;
  for (int i = half; i < cnt; i += 2)
    acc = fmaf(ew[i], agg[(size_t)(s + i) * 128 + d], acc);
  comb[tid] = acc;
  __syncthreads();
  if (half == 0) {
    float r2 = acc + comb[128 + tid];
    q_star[(size_t)g * 256 + d] = q[(size_t)g * 128 + d];
    q_star[(size_t)g * 256 + 128 + d] = r2;
  }
}

__global__ void k_out(const float* __restrict__ qs, const float* __restrict__ W,
                      const float* __restrict__ bias, const float* __restrict__ pa,
                      float* __restrict__ out) {
  int idx = blockIdx.x * blockDim.x + threadIdx.x;
  if (idx >= N_B * N_DH) return;
  int b = idx >> 12, d = idx & 4095;
  float acc = bias[d];
  const float* q = qs + (size_t)b * 256;
  for (int k = 0; k < 256; ++k) acc = fmaf(q[k], W[(size_t)k * 4096 + d], acc);
  float a = pa[0];
  out[idx] = acc >= 0.f ? acc : a * acc;
}

// ---------------- workspace layout (float offsets) ----------------
enum : size_t {
  OFF_X0 = 0,
  OFF_HA = OFF_X0 + (size_t)N_N * 64,
  OFF_HB = OFF_HA + (size_t)N_N * 64,
  OFF_EF = OFF_HB + (size_t)N_N * 64,
  OFF_AMSG0 = OFF_EF + (size_t)N_E * 16,
  OFF_AMSG1 = OFF_AMSG0 + (size_t)N_E * 64,
  OFF_NACC0 = OFF_AMSG1 + (size_t)N_E * 64,
  OFF_NACC1 = OFF_NACC0 + (size_t)N_N * 64,
  OFF_AGG = OFF_NACC1 + (size_t)N_N * 64,
  OFF_QSTAR = OFF_AGG + (size_t)N_N * 128,  // zero block: qstar + 8 state bufs
  OFF_H0A = OFF_QSTAR + N_B * 256,
  OFF_H0B = OFF_H0A + N_B * 128,
  OFF_C0A = OFF_H0B + N_B * 128,
  OFF_C0B = OFF_C0A + N_B * 128,
  OFF_H1A = OFF_C0B + N_B * 128,
  OFF_H1B = OFF_H1A + N_B * 128,
  OFF_C1A = OFF_H1B + N_B * 128,
  OFF_C1B = OFF_C1A + N_B * 128,
  OFF_GSTART = OFF_C1B + N_B * 128,
  OFF_GEND = OFF_GSTART + N_B,
  OFF_WANG = (OFF_GEND + N_B + 63) & ~(size_t)63,  // 48000*8 f32
  OFF_TT_ANG = OFF_WANG + 384000,
  OFF_TT_BOND = OFF_TT_ANG + 34816,
  OFF_WT_AU = OFF_TT_BOND + 34816,
  OFF_WT_BU = OFF_WT_AU + 2048,
  OFF_W3T = OFF_WT_BU + 2048,
  OFF_P8 = OFF_W3T + 16384,              // 12000*512 h16 = 3072000 floats
  OFF_Q = OFF_P8 + 3072000,              // 12000*64 f32
  WS_FLOATS = OFF_Q + 768000
};

extern "C" void kernel_launch(void* const* d_in, const int* in_sizes, int n_in,
                              void* d_out, int out_size, void* d_ws, size_t ws_size,
                              hipStream_t stream) {
  (void)in_sizes; (void)n_in; (void)out_size; (void)ws_size;
  const float* na    = (const float*)d_in[0];
  const float* ea    = (const float*)d_in[1];
  const float* el    = (const float*)d_in[2];
  const float* ang   = (const float*)d_in[3];
  const int*   esrc  = (const int*)d_in[4];
  const int*   edst  = (const int*)d_in[5];
  const int*   asrc  = (const int*)d_in[6];
  const int*   adst  = (const int*)d_in[7];
  const int*   gid   = (const int*)d_in[8];
  const float* projW = (const float*)d_in[9];
  const float* projb = (const float*)d_in[10];
  const float* bondW = (const float*)d_in[11];
  const float* bondb = (const float*)d_in[12];
  const float* efW   = (const float*)d_in[13];
  const float* efb   = (const float*)d_in[14];
  const float* gnnb  = (const float*)d_in[15];
  const float* buW   = (const float*)d_in[16];
  const float* bub   = (const float*)d_in[17];
  const float* auW   = (const float*)d_in[18];
  const float* aub   = (const float*)d_in[19];
  const float* gWih  = (const float*)d_in[20];
  const float* gWhh  = (const float*)d_in[21];
  const float* gbih  = (const float*)d_in[22];
  const float* gbhh  = (const float*)d_in[23];
  const float* sWih0 = (const float*)d_in[24];
  const float* sWhh0 = (const float*)d_in[25];
  const float* sbih0 = (const float*)d_in[26];
  const float* sbhh0 = (const float*)d_in[27];
  const float* sWih1 = (const float*)d_in[28];
  const float* sWhh1 = (const float*)d_in[29];
  const float* sbih1 = (const float*)d_in[30];
  const float* sbhh1 = (const float*)d_in[31];
  const float* spW   = (const float*)d_in[32];
  const float* spb   = (const float*)d_in[33];
  const float* pa    = (const float*)d_in[34];
  float* out = (float*)d_out;
  float* ws = (float*)d_ws;

  float* x0    = ws + OFF_X0;
  float* hA    = ws + OFF_HA;
  float* hB    = ws + OFF_HB;
  float* ef    = ws + OFF_EF;
  float* amsg0 = ws + OFF_AMSG0;
  float* amsg1 = ws + OFF_AMSG1;
  float* nacc0 = ws + OFF_NACC0;
  float* nacc1 = ws + OFF_NACC1;
  float* agg   = ws + OFF_AGG;
  float* qstar = ws + OFF_QSTAR;
  float* h0a = ws + OFF_H0A; float* h0b = ws + OFF_H0B;
  float* c0a = ws + OFF_C0A; float* c0b = ws + OFF_C0B;
  float* h1a = ws + OFF_H1A; float* h1b = ws + OFF_H1B;
  float* c1a = ws + OFF_C1A; float* c1b = ws + OFF_C1B;
  int* gstart  = (int*)(ws + OFF_GSTART);
  float* wang = ws + OFF_WANG;
  h16* ttA  = (h16*)(ws + OFF_TT_ANG);
  h16* ttB  = (h16*)(ws + OFF_TT_BOND);
  h16* wtAU = (h16*)(ws + OFF_WT_AU);
  h16* wtBU = (h16*)(ws + OFF_WT_BU);
  h16* w3t  = (h16*)(ws + OFF_W3T);
  h16* P8   = (h16*)(ws + OFF_P8);
  float* Q    = ws + OFF_Q;

  hipMemsetAsync(gstart, 0x7f, 2 * N_B * sizeof(int), stream);
  k_setup<<<SB_END, 256, 0, stream>>>(
      na, projW, projb, ea, el, ang, gid, gWih, gWhh, efW, efb, bondW, bondb,
      auW, buW, x0, ef, wang, gstart, gstart + N_B, w3t, ttA, ttB, wtAU, wtBU,
      (float4*)amsg0, (float4*)nacc0, (float4*)qstar);

  const int EGX = (N_E + 63) / 64;
  const float* cur = x0;
  float* bufs[2] = {hA, hB};
  float* amsgs[2] = {amsg0, amsg1};
  float* naccs[2] = {nacc0, nacc1};
  for (int s = 0; s < 4; ++s) {
    float* amsg_c = amsgs[s & 1];
    float* amsg_o = amsgs[(s + 1) & 1];
    float* nacc_c = naccs[s & 1];
    float* nacc_o = naccs[(s + 1) & 1];
    k_edgeP<<<dim3(EGX, 4), 256, 0, stream>>>(cur, esrc, wtAU, aub, ttA, ef, P8, Q);
    k_angle<<<(N_A * 64) / 256, 256, 0, stream>>>(wang, asrc, adst, P8, Q, amsg_c);
    k_bond<<<dim3(EGX, 4), 256, 0, stream>>>(cur, esrc, wtBU, bub, amsg_c, ef, ttB,
                                             edst, nacc_c, (float4*)amsg_o,
                                             N_E * 64 / 4);
    float* nxt = bufs[s & 1];
    k_gru2<<<(N_N + 31) / 32, 128, 0, stream>>>(nacc_c, gnnb, cur, w3t, gbih, gbhh,
                                                nxt, x0, agg, (s == 3) ? 1 : 0,
                                                (float4*)nacc_o, N_N * 64 / 4);
    cur = nxt;
  }

  // ---- Set2Set (qstar/h/c zeroed by k_setup) ----
  float *h0i = h0a, *h0o = h0b, *c0i = c0a, *c0o = c0b;
  float *h1i = h1a, *h1o = h1b, *c1i = c1a, *c1o = c1b;
  for (int it = 0; it < 3; ++it) {
    k_lstm2<<<(N_B * 128 * 64 + 255) / 256, 256, 0, stream>>>(
        qstar, 256, h0i, c0i, sWih0, sWhh0, sbih0, sbhh0, h0o, c0o);
    k_lstm2<<<(N_B * 128 * 64 + 255) / 256, 256, 0, stream>>>(
        h0o, 128, h1i, c1i, sWih1, sWhh1, sbih1, sbhh1, h1o, c1o);
    k_pool2<<<N_B, 256, 0, stream>>>(agg, gstart, gstart + N_B, h1o, qstar);
    float* tmp;
    tmp = h0i; h0i = h0o; h0o = tmp;
    tmp = c0i; c0i = c0o; c0o = tmp;
    tmp = h1i; h1i = h1o; h1o = tmp;
    tmp = c1i; c1i = c1o; c1o = tmp;
  }
  k_out<<<(N_B * N_DH + 255) / 256, 256, 0, stream>>>(qstar, spW, spb, pa, out);
}

// Round 12
// 391.306 us; speedup vs baseline: 1.0642x; 1.0642x over previous
//
#include <hip/hip_runtime.h>
#include <math.h>

#define N_N 8000
#define N_E 12000
#define N_A 48000
#define N_B 64
#define N_H 64
#define N_DH 4096

typedef _Float16 h16;
typedef __attribute__((ext_vector_type(8))) _Float16 h16x8;
typedef __attribute__((ext_vector_type(4))) float f32x4;

__device__ __forceinline__ float atomAddF(float* p, float v) {
  return __hip_atomic_fetch_add(p, v, __ATOMIC_RELAXED, __HIP_MEMORY_SCOPE_AGENT);
}
__device__ __forceinline__ float sigm(float x) { return 1.f / (1.f + expf(-x)); }

// ---------------- mega setup kernel ----------------
// ranges: proj | ef-feat | wang | prep | bounds | zero(amsg0,nacc0,qstar-block)
#define SB_PROJ 2000
#define SB_FEAT (SB_PROJ + 47)
#define SB_WANG (SB_FEAT + 188)
#define SB_PREP (SB_WANG + 704)
#define SB_BND  (SB_PREP + 32)
#define SB_END  (SB_BND + 1330)
#define PREP_B0 32768                 // w3t   [256][128]
#define PREP_B1 (PREP_B0 + 69632)     // ttA   [1088][64]
#define PREP_B2 (PREP_B1 + 69632)     // ttB   [1088][64]
#define PREP_B3 (PREP_B2 + 4096)      // wtAU  [64][64]
#define PREP_B4 (PREP_B3 + 4096)      // wtBU  [64][64]

__global__ __launch_bounds__(256) void k_setup(
    const float* __restrict__ na, const float* __restrict__ projW,
    const float* __restrict__ projb, const float* __restrict__ ea,
    const float* __restrict__ el, const float* __restrict__ ang,
    const int* __restrict__ gid,
    const float* __restrict__ gWih, const float* __restrict__ gWhh,
    const float* __restrict__ efW, const float* __restrict__ efb,
    const float* __restrict__ bondW, const float* __restrict__ bondb,
    const float* __restrict__ auW, const float* __restrict__ buW,
    float* __restrict__ x0, float* __restrict__ ef, float* __restrict__ wang,
    int* __restrict__ gstart, int* __restrict__ gend,
    h16* __restrict__ W3t, h16* __restrict__ ttA, h16* __restrict__ ttB,
    h16* __restrict__ wtAU, h16* __restrict__ wtBU,
    float4* __restrict__ amsg0_4, float4* __restrict__ nacc0_4,
    float4* __restrict__ qz_4) {
  int bx = blockIdx.x, tid = threadIdx.x;
  if (bx < SB_PROJ) {
    int wid = bx * 4 + (tid >> 6);
    int lane = tid & 63;
    if (wid < N_N) {
      const float* row = na + (size_t)wid * 110;
      float acc = projb[lane];
      for (int k = 0; k < 110; ++k) acc = fmaf(row[k], projW[k * 64 + lane], acc);
      x0[(size_t)wid * 64 + lane] = fmaxf(acc, 0.f);
    }
  } else if (bx < SB_FEAT) {
    int e = (bx - SB_PROJ) * 256 + tid;
    if (e < N_E) {
      const float g2 = (7.f / 4.f) * (7.f / 4.f);
      float x = el[e];
#pragma unroll
      for (int j = 0; j < 8; ++j) ef[e * 16 + j] = ea[e * 8 + j];
#pragma unroll
      for (int j = 0; j < 8; ++j) {
        float d = x - j * (4.f / 7.f);
        ef[e * 16 + 8 + j] = expf(-g2 * d * d);
      }
    }
  } else if (bx < SB_WANG) {
    int a = (bx - SB_FEAT) * 256 + tid;
    if (a < N_A) {
      const float PIf = 3.14159265358979323846f;
      const float g1 = (7.f / PIf) * (7.f / PIf);
      float x = ang[a];
#pragma unroll
      for (int j = 0; j < 8; ++j) {
        float d = x - j * (PIf / 7.f);
        wang[(size_t)a * 8 + j] = expf(-g1 * d * d);
      }
    }
  } else if (bx < SB_PREP) {
    int i = (bx - SB_WANG) * 256 + tid;
    if (i < PREP_B0) {
      int col = i >> 7, k = i & 127;
      int grp = col >> 6, u = col & 63;
      float v;
      if (grp == 0) v = (k < 64) ? gWih[u * 64 + k] : gWhh[u * 64 + k - 64];
      else if (grp == 1) v = (k < 64) ? gWih[(64 + u) * 64 + k] : gWhh[(64 + u) * 64 + k - 64];
      else if (grp == 2) v = (k < 64) ? gWih[(128 + u) * 64 + k] : 0.f;
      else v = (k < 64) ? 0.f : gWhh[(128 + u) * 64 + k - 64];
      W3t[i] = (h16)v;
    } else if (i < PREP_B1) {
      int j = i - PREP_B0;
      int n = j >> 6, i2 = j & 63;
      int k = n >> 6, o = n & 63;
      float val = (k < 16) ? efW[(size_t)k * 4096 + i2 * 64 + o] : efb[i2 * 64 + o];
      ttA[j] = (h16)val;
    } else if (i < PREP_B2) {
      int j = i - PREP_B1;
      int n = j >> 6, i2 = j & 63;
      int k = n >> 6, o = n & 63;
      float val = (k < 16) ? bondW[(size_t)k * 4096 + i2 * 64 + o] : bondb[i2 * 64 + o];
      ttB[j] = (h16)val;
    } else if (i < PREP_B3) {
      int j = i - PREP_B2;
      int o = j >> 6, i2 = j & 63;
      wtAU[j] = (h16)auW[i2 * 64 + o];
    } else if (i < PREP_B4) {
      int j = i - PREP_B3;
      int o = j >> 6, i2 = j & 63;
      wtBU[j] = (h16)buW[i2 * 64 + o];
    }
  } else if (bx < SB_BND) {
    int n = (bx - SB_PREP) * 256 + tid;
    if (n < N_N) {
      int g = gid[n];
      if (n == 0 || gid[n - 1] != g) gstart[g] = n;
      if (n == N_N - 1 || gid[n + 1] != g) gend[g] = n + 1;
    }
  } else if (bx < SB_END) {
    int i = (bx - SB_BND) * 256 + tid;
    float4 z = (float4){0.f, 0.f, 0.f, 0.f};
    if (i < 192000) amsg0_4[i] = z;
    else if (i < 320000) nacc0_4[i - 192000] = z;
    else if (i < 340480) qz_4[i - 320000] = z;
  }
}

// ---------------- per-edge P8/Q precompute ----------------
// ha[e] = relu(x[esrc[e]]@auW+aub) (inline MFMA, swizzled-LDS relayout)
// P8[e][kk][o] = ha[e] @ ttA[kk*64+o]           kk = 0..7   (angle-rbf slices)
// Q[e][o]     = sum_{j<8} lenrbf[e][j]*(ha@ttA[(8+j)*64+o]) + ha@ttA[16*64+o]
// blockIdx.y: 0: P8 kk0-3 | 1: P8 kk4-7 | 2: Q o0-31 | 3: Q o32-63
__global__ __launch_bounds__(256) void k_edgeP(
    const float* __restrict__ xcur, const int* __restrict__ esrc,
    const h16* __restrict__ wtAU, const float* __restrict__ aub,
    const h16* __restrict__ ttA, const float* __restrict__ ef,
    h16* __restrict__ P8, float* __restrict__ Q) {
  __shared__ h16 haT[4][2048];
  __shared__ float f_lds[128 * 9];
  int tid = threadIdx.x, wave = tid >> 6, lane = tid & 63;
  int l15 = lane & 15, lq = lane >> 4;
  int oc = blockIdx.y;
  int base = blockIdx.x * 128;
  if (oc >= 2) {
    for (int e2 = tid; e2 < 128 * 8; e2 += 256) {
      int il = e2 >> 3, k = e2 & 7;
      int g = base + il;
      if (g >= N_E) g = N_E - 1;
      f_lds[il * 9 + k] = ef[(size_t)g * 16 + 8 + k];
    }
    __syncthreads();
  }
  int ibl = wave * 32, ib0 = base + ibl;
  h16* myT = haT[wave];

  // inline MLP (full 64 outs)
  {
    h16x8 xafr[2][2];
#pragma unroll
    for (int s = 0; s < 2; ++s) {
      int item = ib0 + s * 16 + l15;
      if (item >= N_E) item = N_E - 1;
      const float* vp = xcur + (size_t)esrc[item] * 64;
#pragma unroll
      for (int ks = 0; ks < 2; ++ks) {
        const float4* p = (const float4*)(vp + ks * 32 + 8 * lq);
        float4 v0 = p[0], v1 = p[1];
        h16x8 a;
        a[0] = (h16)v0.x; a[1] = (h16)v0.y; a[2] = (h16)v0.z; a[3] = (h16)v0.w;
        a[4] = (h16)v1.x; a[5] = (h16)v1.y; a[6] = (h16)v1.z; a[7] = (h16)v1.w;
        xafr[s][ks] = a;
      }
    }
    f32x4 aU[2][4];
#pragma unroll
    for (int s = 0; s < 2; ++s)
#pragma unroll
      for (int nt = 0; nt < 4; ++nt) aU[s][nt] = (f32x4){0.f, 0.f, 0.f, 0.f};
#pragma unroll
    for (int nt = 0; nt < 4; ++nt)
#pragma unroll
      for (int ks = 0; ks < 2; ++ks) {
        h16x8 b = *(const h16x8*)(wtAU + (size_t)(nt * 16 + l15) * 64 + ks * 32 + 8 * lq);
#pragma unroll
        for (int s = 0; s < 2; ++s)
          aU[s][nt] = __builtin_amdgcn_mfma_f32_16x16x32_f16(xafr[s][ks], b, aU[s][nt], 0, 0, 0);
      }
#pragma unroll
    for (int s = 0; s < 2; ++s)
#pragma unroll
      for (int nt = 0; nt < 4; ++nt) {
        int o = nt * 16 + l15;
        float bo = aub[o];
#pragma unroll
        for (int r = 0; r < 4; ++r) {
          int row = s * 16 + lq * 4 + r;
          float val = fmaxf(aU[s][nt][r] + bo, 0.f);
          int idx = (((row * 64 + o) << 1) ^ ((row & 7) << 4)) >> 1;
          myT[idx] = (h16)val;
        }
      }
  }
  h16x8 afr[2][2];
#pragma unroll
  for (int s = 0; s < 2; ++s)
#pragma unroll
    for (int ks = 0; ks < 2; ++ks) {
      int row = s * 16 + l15;
      int byte = ((row * 64 + ks * 32 + 8 * lq) << 1) ^ ((row & 7) << 4);
      afr[s][ks] = *(const h16x8*)((const char*)myT + byte);
    }

  if (oc < 2) {
#pragma unroll
    for (int kk = oc * 4; kk < oc * 4 + 4; ++kk) {
      f32x4 acc[2][4];
#pragma unroll
      for (int s = 0; s < 2; ++s)
#pragma unroll
        for (int nt = 0; nt < 4; ++nt) acc[s][nt] = (f32x4){0.f, 0.f, 0.f, 0.f};
#pragma unroll
      for (int nt = 0; nt < 4; ++nt)
#pragma unroll
        for (int ks = 0; ks < 2; ++ks) {
          h16x8 b = *(const h16x8*)(ttA + (size_t)(kk * 64 + nt * 16 + l15) * 64 +
                                    ks * 32 + 8 * lq);
#pragma unroll
          for (int s = 0; s < 2; ++s)
            acc[s][nt] = __builtin_amdgcn_mfma_f32_16x16x32_f16(afr[s][ks], b, acc[s][nt], 0, 0, 0);
        }
#pragma unroll
      for (int s = 0; s < 2; ++s)
#pragma unroll
        for (int r = 0; r < 4; ++r) {
          int e = ib0 + s * 16 + lq * 4 + r;
          if (e < N_E) {
#pragma unroll
            for (int nt = 0; nt < 4; ++nt)
              P8[((size_t)e * 8 + kk) * 64 + nt * 16 + l15] = (h16)acc[s][nt][r];
          }
        }
    }
  } else {
    int no = oc - 2;
    f32x4 qacc[2][2];
#pragma unroll
    for (int s = 0; s < 2; ++s)
#pragma unroll
      for (int nt = 0; nt < 2; ++nt) qacc[s][nt] = (f32x4){0.f, 0.f, 0.f, 0.f};
    for (int kk = 8; kk < 16; ++kk) {
      h16x8 a2[2][2];
#pragma unroll
      for (int s = 0; s < 2; ++s) {
        h16 fs = (h16)f_lds[(ibl + s * 16 + l15) * 9 + (kk - 8)];
        a2[s][0] = afr[s][0] * fs;
        a2[s][1] = afr[s][1] * fs;
      }
#pragma unroll
      for (int nt = 0; nt < 2; ++nt)
#pragma unroll
        for (int ks = 0; ks < 2; ++ks) {
          h16x8 b = *(const h16x8*)(ttA + (size_t)(kk * 64 + (no * 2 + nt) * 16 + l15) * 64 +
                                    ks * 32 + 8 * lq);
#pragma unroll
          for (int s = 0; s < 2; ++s)
            qacc[s][nt] = __builtin_amdgcn_mfma_f32_16x16x32_f16(a2[s][ks], b, qacc[s][nt], 0, 0, 0);
        }
    }
#pragma unroll
    for (int nt = 0; nt < 2; ++nt)
#pragma unroll
      for (int ks = 0; ks < 2; ++ks) {
        h16x8 b = *(const h16x8*)(ttA + (size_t)(16 * 64 + (no * 2 + nt) * 16 + l15) * 64 +
                                  ks * 32 + 8 * lq);
#pragma unroll
        for (int s = 0; s < 2; ++s)
          qacc[s][nt] = __builtin_amdgcn_mfma_f32_16x16x32_f16(afr[s][ks], b, qacc[s][nt], 0, 0, 0);
      }
#pragma unroll
    for (int s = 0; s < 2; ++s)
#pragma unroll
      for (int r = 0; r < 4; ++r) {
        int e = ib0 + s * 16 + lq * 4 + r;
        if (e < N_E) {
#pragma unroll
          for (int nt = 0; nt < 2; ++nt)
            Q[(size_t)e * 64 + (no * 2 + nt) * 16 + l15] = qacc[s][nt][r];
        }
      }
  }
}

// ---------------- per-angle gather + scatter (wang table, no expf) ----------------
__global__ __launch_bounds__(256) void k_angle(
    const float* __restrict__ wang, const int* __restrict__ asrc,
    const int* __restrict__ adst, const h16* __restrict__ P8,
    const float* __restrict__ Q, float* __restrict__ amsg) {
  int w = (blockIdx.x * blockDim.x + threadIdx.x) >> 6;
  int lane = threadIdx.x & 63;
  if (w >= N_A) return;
  int e = asrc[w], d = adst[w];
  float acc = Q[(size_t)e * 64 + lane];
  const h16* p = P8 + (size_t)e * 512;
  const float4* wp = (const float4*)(wang + (size_t)w * 8);
  float4 w0 = wp[0], w1 = wp[1];
  acc = fmaf(w0.x, (float)p[0 * 64 + lane], acc);
  acc = fmaf(w0.y, (float)p[1 * 64 + lane], acc);
  acc = fmaf(w0.z, (float)p[2 * 64 + lane], acc);
  acc = fmaf(w0.w, (float)p[3 * 64 + lane], acc);
  acc = fmaf(w1.x, (float)p[4 * 64 + lane], acc);
  acc = fmaf(w1.y, (float)p[5 * 64 + lane], acc);
  acc = fmaf(w1.z, (float)p[6 * 64 + lane], acc);
  acc = fmaf(w1.w, (float)p[7 * 64 + lane], acc);
  atomAddF(amsg + (size_t)d * 64 + lane, acc);
}

// ---------------- bond: inline MLP(+amsg) + 17-slice contraction + scatter ----
// blockIdx.y = o-quarter (16 outs). Zeroes zbuf via y==0 blocks.
__global__ __launch_bounds__(256) void k_bond(
    const float* __restrict__ xcur, const int* __restrict__ esrc,
    const h16* __restrict__ wtBU, const float* __restrict__ bub,
    const float* __restrict__ amsg_in, const float* __restrict__ ef,
    const h16* __restrict__ ttB, const int* __restrict__ edst,
    float* __restrict__ nacc, float4* __restrict__ zbuf, int zcount4) {
  if (blockIdx.y == 0) {
    int stride = gridDim.x * 256;
    for (int i = blockIdx.x * 256 + threadIdx.x; i < zcount4; i += stride)
      zbuf[i] = (float4){0.f, 0.f, 0.f, 0.f};
  }
  __shared__ h16 haT[4][2048];
  __shared__ float f_lds[128 * 17];
  __shared__ int dst_lds[128];
  int tid = threadIdx.x;
  int base = blockIdx.x * 128;
  int oc = blockIdx.y;
  for (int e2 = tid; e2 < 128 * 16; e2 += 256) {
    int il = e2 >> 4, k = e2 & 15;
    int g = base + il;
    if (g >= N_E) g = N_E - 1;
    f_lds[il * 17 + k] = ef[(size_t)g * 16 + k];
  }
  if (tid < 128) {
    int g = base + tid;
    if (g >= N_E) g = N_E - 1;
    dst_lds[tid] = edst[g];
  }
  __syncthreads();

  int wave = tid >> 6, lane = tid & 63;
  int l15 = lane & 15, lq = lane >> 4;
  int ibl = wave * 32, ib0 = base + ibl;
  h16* myT = haT[wave];

  {
    h16x8 xafr[2][2];
#pragma unroll
    for (int s = 0; s < 2; ++s) {
      int item = ib0 + s * 16 + l15;
      if (item >= N_E) item = N_E - 1;
      const float* vp = xcur + (size_t)esrc[item] * 64;
#pragma unroll
      for (int ks = 0; ks < 2; ++ks) {
        const float4* p = (const float4*)(vp + ks * 32 + 8 * lq);
        float4 v0 = p[0], v1 = p[1];
        h16x8 a;
        a[0] = (h16)v0.x; a[1] = (h16)v0.y; a[2] = (h16)v0.z; a[3] = (h16)v0.w;
        a[4] = (h16)v1.x; a[5] = (h16)v1.y; a[6] = (h16)v1.z; a[7] = (h16)v1.w;
        xafr[s][ks] = a;
      }
    }
    f32x4 aU[2][4];
#pragma unroll
    for (int s = 0; s < 2; ++s)
#pragma unroll
      for (int nt = 0; nt < 4; ++nt) aU[s][nt] = (f32x4){0.f, 0.f, 0.f, 0.f};
#pragma unroll
    for (int nt = 0; nt < 4; ++nt)
#pragma unroll
      for (int ks = 0; ks < 2; ++ks) {
        h16x8 b = *(const h16x8*)(wtBU + (size_t)(nt * 16 + l15) * 64 + ks * 32 + 8 * lq);
#pragma unroll
        for (int s = 0; s < 2; ++s)
          aU[s][nt] = __builtin_amdgcn_mfma_f32_16x16x32_f16(xafr[s][ks], b, aU[s][nt], 0, 0, 0);
      }
#pragma unroll
    for (int s = 0; s < 2; ++s)
#pragma unroll
      for (int nt = 0; nt < 4; ++nt) {
        int o = nt * 16 + l15;
        float bo = bub[o];
#pragma unroll
        for (int r = 0; r < 4; ++r) {
          int row = s * 16 + lq * 4 + r;
          int item = ib0 + row;
          if (item >= N_E) item = N_E - 1;
          float val = fmaxf(aU[s][nt][r] + bo, 0.f) + amsg_in[(size_t)item * 64 + o];
          int idx = (((row * 64 + o) << 1) ^ ((row & 7) << 4)) >> 1;
          myT[idx] = (h16)val;
        }
      }
  }
  h16x8 afr[2][2];
#pragma unroll
  for (int s = 0; s < 2; ++s)
#pragma unroll
    for (int ks = 0; ks < 2; ++ks) {
      int row = s * 16 + l15;
      int byte = ((row * 64 + ks * 32 + 8 * lq) << 1) ^ ((row & 7) << 4);
      afr[s][ks] = *(const h16x8*)((const char*)myT + byte);
    }

  f32x4 acc[2];
  acc[0] = (f32x4){0.f, 0.f, 0.f, 0.f};
  acc[1] = (f32x4){0.f, 0.f, 0.f, 0.f};
  for (int kk = 0; kk < 16; ++kk) {
    h16x8 bfr[2];
#pragma unroll
    for (int ks = 0; ks < 2; ++ks)
      bfr[ks] = *(const h16x8*)(ttB + (size_t)(kk * 64 + oc * 16 + l15) * 64 + ks * 32 + 8 * lq);
    h16x8 a2[2][2];
#pragma unroll
    for (int s = 0; s < 2; ++s) {
      h16 fs = (h16)f_lds[(ibl + s * 16 + l15) * 17 + kk];
      a2[s][0] = afr[s][0] * fs;
      a2[s][1] = afr[s][1] * fs;
    }
#pragma unroll
    for (int s = 0; s < 2; ++s)
#pragma unroll
      for (int ks = 0; ks < 2; ++ks)
        acc[s] = __builtin_amdgcn_mfma_f32_16x16x32_f16(a2[s][ks], bfr[ks], acc[s], 0, 0, 0);
  }
  {
    h16x8 bfr[2];
#pragma unroll
    for (int ks = 0; ks < 2; ++ks)
      bfr[ks] = *(const h16x8*)(ttB + (size_t)(16 * 64 + oc * 16 + l15) * 64 + ks * 32 + 8 * lq);
#pragma unroll
    for (int s = 0; s < 2; ++s)
#pragma unroll
      for (int ks = 0; ks < 2; ++ks)
        acc[s] = __builtin_amdgcn_mfma_f32_16x16x32_f16(afr[s][ks], bfr[ks], acc[s], 0, 0, 0);
  }
#pragma unroll
  for (int s = 0; s < 2; ++s)
#pragma unroll
    for (int r = 0; r < 4; ++r) {
      int il = ibl + s * 16 + lq * 4 + r;
      int item = base + il;
      if (item < N_E)
        atomAddF(nacc + (size_t)dst_lds[il] * 64 + oc * 16 + l15, acc[s][r]);
    }
}

// ---------------- MFMA GRU (32 nodes/block, 2 waves -> 250 blocks) ----------------
__global__ __launch_bounds__(128) void k_gru2(
    const float* __restrict__ nacc, const float* __restrict__ gnnb,
    const float* __restrict__ h, const h16* __restrict__ W3t,
    const float* __restrict__ gbih, const float* __restrict__ gbhh,
    float* __restrict__ hout, const float* __restrict__ x0,
    float* __restrict__ agg, int wagg, float4* __restrict__ zbuf, int zcount4) {
  if (zbuf) {
    int stride = gridDim.x * 128;
    for (int i = blockIdx.x * 128 + threadIdx.x; i < zcount4; i += stride)
      zbuf[i] = (float4){0.f, 0.f, 0.f, 0.f};
  }
  int tid = threadIdx.x, wave = tid >> 6, lane = tid & 63;
  int l15 = lane & 15, lq = lane >> 4;
  int ib0 = blockIdx.x * 32 + wave * 16;
  int nodeA = ib0 + l15;
  if (nodeA >= N_N) nodeA = N_N - 1;

  h16x8 afr[4];
#pragma unroll
  for (int ks = 0; ks < 2; ++ks) {
    const float4* p = (const float4*)(nacc + (size_t)nodeA * 64 + ks * 32 + 8 * lq);
    const float4* gp = (const float4*)(gnnb + ks * 32 + 8 * lq);
    float4 v0 = p[0], v1 = p[1], g0 = gp[0], g1 = gp[1];
    h16x8 a;
    a[0] = (h16)fmaxf(v0.x + g0.x, 0.f); a[1] = (h16)fmaxf(v0.y + g0.y, 0.f);
    a[2] = (h16)fmaxf(v0.z + g0.z, 0.f); a[3] = (h16)fmaxf(v0.w + g0.w, 0.f);
    a[4] = (h16)fmaxf(v1.x + g1.x, 0.f); a[5] = (h16)fmaxf(v1.y + g1.y, 0.f);
    a[6] = (h16)fmaxf(v1.z + g1.z, 0.f); a[7] = (h16)fmaxf(v1.w + g1.w, 0.f);
    afr[ks] = a;
  }
#pragma unroll
  for (int ks = 0; ks < 2; ++ks) {
    const float4* p = (const float4*)(h + (size_t)nodeA * 64 + ks * 32 + 8 * lq);
    float4 v0 = p[0], v1 = p[1];
    h16x8 a;
    a[0] = (h16)v0.x; a[1] = (h16)v0.y; a[2] = (h16)v0.z; a[3] = (h16)v0.w;
    a[4] = (h16)v1.x; a[5] = (h16)v1.y; a[6] = (h16)v1.z; a[7] = (h16)v1.w;
    afr[2 + ks] = a;
  }

  f32x4 acc[16];
#pragma unroll
  for (int nt = 0; nt < 16; ++nt) acc[nt] = (f32x4){0.f, 0.f, 0.f, 0.f};
#pragma unroll
  for (int nt = 0; nt < 16; ++nt) {
#pragma unroll
    for (int ks = 0; ks < 4; ++ks) {
      if (nt >= 8 && nt < 12 && ks >= 2) continue;
      if (nt >= 12 && ks < 2) continue;
      h16x8 b = *(const h16x8*)(W3t + (size_t)(nt * 16 + l15) * 128 + ks * 32 + 8 * lq);
      acc[nt] = __builtin_amdgcn_mfma_f32_16x16x32_f16(afr[ks], b, acc[nt], 0, 0, 0);
    }
  }

#pragma unroll
  for (int nt0 = 0; nt0 < 4; ++nt0) {
    int u = nt0 * 16 + l15;
    float br = gbih[u] + gbhh[u];
    float bz = gbih[64 + u] + gbhh[64 + u];
    float bin_ = gbih[128 + u];
    float bhn = gbhh[128 + u];
#pragma unroll
    for (int r = 0; r < 4; ++r) {
      int node = ib0 + lq * 4 + r;
      if (node < N_N) {
        float rr = sigm(acc[nt0][r] + br);
        float zz = sigm(acc[nt0 + 4][r] + bz);
        float nn = tanhf(acc[nt0 + 8][r] + bin_ + rr * (acc[nt0 + 12][r] + bhn));
        float hv = h[(size_t)node * 64 + u];
        float val = (1.f - zz) * nn + zz * hv;
        hout[(size_t)node * 64 + u] = val;
        if (wagg) {
          agg[(size_t)node * 128 + u] = val;
          agg[(size_t)node * 128 + 64 + u] = x0[(size_t)node * 64 + u];
        }
      }
    }
  }
}

// ---------------- Set2Set (split kernels — measured-good) ----------------

__global__ __launch_bounds__(256) void k_lstm2(
    const float* __restrict__ x, int xdim,
    const float* __restrict__ hin, const float* __restrict__ cin,
    const float* __restrict__ Wih, const float* __restrict__ Whh,
    const float* __restrict__ bih, const float* __restrict__ bhh,
    float* __restrict__ hout, float* __restrict__ cout) {
  int w = (blockIdx.x * blockDim.x + threadIdx.x) >> 6;
  int lane = threadIdx.x & 63;
  if (w >= N_B * 128) return;
  int b = w >> 7, u = w & 127;
  float a0 = 0.f, a1 = 0.f, a2 = 0.f, a3 = 0.f;
  const float* xr = x + (size_t)b * xdim;
  for (int k = lane; k < xdim; k += 64) {
    float xv = xr[k];
    a0 = fmaf(xv, Wih[(size_t)u * xdim + k], a0);
    a1 = fmaf(xv, Wih[(size_t)(128 + u) * xdim + k], a1);
    a2 = fmaf(xv, Wih[(size_t)(256 + u) * xdim + k], a2);
    a3 = fmaf(xv, Wih[(size_t)(384 + u) * xdim + k], a3);
  }
  const float* hr = hin + (size_t)b * 128;
#pragma unroll
  for (int k0 = 0; k0 < 128; k0 += 64) {
    int k = k0 + lane;
    float hv = hr[k];
    a0 = fmaf(hv, Whh[(size_t)u * 128 + k], a0);
    a1 = fmaf(hv, Whh[(size_t)(128 + u) * 128 + k], a1);
    a2 = fmaf(hv, Whh[(size_t)(256 + u) * 128 + k], a2);
    a3 = fmaf(hv, Whh[(size_t)(384 + u) * 128 + k], a3);
  }
#pragma unroll
  for (int mm = 1; mm < 64; mm <<= 1) {
    a0 += __shfl_xor(a0, mm);
    a1 += __shfl_xor(a1, mm);
    a2 += __shfl_xor(a2, mm);
    a3 += __shfl_xor(a3, mm);
  }
  if (lane == 0) {
    float gi = a0 + bih[u] + bhh[u];
    float gf = a1 + bih[128 + u] + bhh[128 + u];
    float gg = a2 + bih[256 + u] + bhh[256 + u];
    float go = a3 + bih[384 + u] + bhh[384 + u];
    float c2 = sigm(gf) * cin[(size_t)b * 128 + u] + sigm(gi) * tanhf(gg);
    hout[(size_t)b * 128 + u] = sigm(go) * tanhf(c2);
    cout[(size_t)b * 128 + u] = c2;
  }
}

__global__ __launch_bounds__(256) void k_pool2(
    const float* __restrict__ agg, const int* __restrict__ gstart,
    const int* __restrict__ gend, const float* __restrict__ q,
    float* __restrict__ q_star) {
  int g = blockIdx.x;
  int s = gstart[g], t = gend[g];
  int cnt = t - s;
  if (cnt < 0) cnt = 0;
  if (cnt > 1024) cnt = 1024;
  __shared__ float ew[1024];
  __shared__ float red[8];
  __shared__ float comb[256];
  int tid = threadIdx.x, wave = tid >> 6, lane = tid & 63;
  float qa = q[g * 128 + lane], qb = q[g * 128 + 64 + lane];
  for (int i = wave; i < cnt; i += 4) {
    int n = s + i;
    float a = agg[(size_t)n * 128 + lane] * qa + agg[(size_t)n * 128 + 64 + lane] * qb;
#pragma unroll
    for (int mm = 1; mm < 64; mm <<= 1) a += __shfl_xor(a, mm);
    if (lane == 0) ew[i] = a;
  }
  __syncthreads();
  float mx = -INFINITY;
  for (int i = tid; i < cnt; i += 256) mx = fmaxf(mx, ew[i]);
#pragma unroll
  for (int mm = 1; mm < 64; mm <<= 1) mx = fmaxf(mx, __shfl_xor(mx, mm));
  if (lane == 0) red[wave] = mx;
  __syncthreads();
  mx = fmaxf(fmaxf(red[0], red[1]), fmaxf(red[2], red[3]));
  float sm = 0.f;
  for (int i = tid; i < cnt; i += 256) sm += expf(ew[i] - mx);
#pragma unroll
  for (int mm = 1; mm < 64; mm <<= 1) sm += __shfl_xor(sm, mm);
  if (lane == 0) red[4 + wave] = sm;
  __syncthreads();
  sm = red[4] + red[5] + red[6] + red[7];
  float inv = (sm > 0.f) ? 1.f / sm : 0.f;
  __syncthreads();
  for (int i = tid; i < cnt; i += 256) ew[i] = expf(ew[i] - mx) * inv;
  __syncthreads();
  int d = tid & 127, half = tid >> 7;
  float acc = 0.f;
  for (int i = half; i < cnt; i += 2)
    acc = fmaf(ew[i], agg[(size_t)(s + i) * 128 + d], acc);
  comb[tid] = acc;
  __syncthreads();
  if (half == 0) {
    float r2 = acc + comb[128 + tid];
    q_star[(size_t)g * 256 + d] = q[(size_t)g * 128 + d];
    q_star[(size_t)g * 256 + 128 + d] = r2;
  }
}

__global__ void k_out(const float* __restrict__ qs, const float* __restrict__ W,
                      const float* __restrict__ bias, const float* __restrict__ pa,
                      float* __restrict__ out) {
  int idx = blockIdx.x * blockDim.x + threadIdx.x;
  if (idx >= N_B * N_DH) return;
  int b = idx >> 12, d = idx & 4095;
  float acc = bias[d];
  const float* q = qs + (size_t)b * 256;
  for (int k = 0; k < 256; ++k) acc = fmaf(q[k], W[(size_t)k * 4096 + d], acc);
  float a = pa[0];
  out[idx] = acc >= 0.f ? acc : a * acc;
}

// ---------------- workspace layout (float offsets) ----------------
enum : size_t {
  OFF_X0 = 0,
  OFF_HA = OFF_X0 + (size_t)N_N * 64,
  OFF_HB = OFF_HA + (size_t)N_N * 64,
  OFF_EF = OFF_HB + (size_t)N_N * 64,
  OFF_AMSG0 = OFF_EF + (size_t)N_E * 16,
  OFF_AMSG1 = OFF_AMSG0 + (size_t)N_E * 64,
  OFF_NACC0 = OFF_AMSG1 + (size_t)N_E * 64,
  OFF_NACC1 = OFF_NACC0 + (size_t)N_N * 64,
  OFF_AGG = OFF_NACC1 + (size_t)N_N * 64,
  OFF_QSTAR = OFF_AGG + (size_t)N_N * 128,  // zero block: qstar + 8 state bufs
  OFF_H0A = OFF_QSTAR + N_B * 256,
  OFF_H0B = OFF_H0A + N_B * 128,
  OFF_C0A = OFF_H0B + N_B * 128,
  OFF_C0B = OFF_C0A + N_B * 128,
  OFF_H1A = OFF_C0B + N_B * 128,
  OFF_H1B = OFF_H1A + N_B * 128,
  OFF_C1A = OFF_H1B + N_B * 128,
  OFF_C1B = OFF_C1A + N_B * 128,
  OFF_GSTART = OFF_C1B + N_B * 128,
  OFF_GEND = OFF_GSTART + N_B,
  OFF_WANG = (OFF_GEND + N_B + 63) & ~(size_t)63,  // 48000*8 f32
  OFF_TT_ANG = OFF_WANG + 384000,
  OFF_TT_BOND = OFF_TT_ANG + 34816,
  OFF_WT_AU = OFF_TT_BOND + 34816,
  OFF_WT_BU = OFF_WT_AU + 2048,
  OFF_W3T = OFF_WT_BU + 2048,
  OFF_P8 = OFF_W3T + 16384,              // 12000*512 h16 = 3072000 floats
  OFF_Q = OFF_P8 + 3072000,              // 12000*64 f32
  WS_FLOATS = OFF_Q + 768000
};

extern "C" void kernel_launch(void* const* d_in, const int* in_sizes, int n_in,
                              void* d_out, int out_size, void* d_ws, size_t ws_size,
                              hipStream_t stream) {
  (void)in_sizes; (void)n_in; (void)out_size; (void)ws_size;
  const float* na    = (const float*)d_in[0];
  const float* ea    = (const float*)d_in[1];
  const float* el    = (const float*)d_in[2];
  const float* ang   = (const float*)d_in[3];
  const int*   esrc  = (const int*)d_in[4];
  const int*   edst  = (const int*)d_in[5];
  const int*   asrc  = (const int*)d_in[6];
  const int*   adst  = (const int*)d_in[7];
  const int*   gid   = (const int*)d_in[8];
  const float* projW = (const float*)d_in[9];
  const float* projb = (const float*)d_in[10];
  const float* bondW = (const float*)d_in[11];
  const float* bondb = (const float*)d_in[12];
  const float* efW   = (const float*)d_in[13];
  const float* efb   = (const float*)d_in[14];
  const float* gnnb  = (const float*)d_in[15];
  const float* buW   = (const float*)d_in[16];
  const float* bub   = (const float*)d_in[17];
  const float* auW   = (const float*)d_in[18];
  const float* aub   = (const float*)d_in[19];
  const float* gWih  = (const float*)d_in[20];
  const float* gWhh  = (const float*)d_in[21];
  const float* gbih  = (const float*)d_in[22];
  const float* gbhh  = (const float*)d_in[23];
  const float* sWih0 = (const float*)d_in[24];
  const float* sWhh0 = (const float*)d_in[25];
  const float* sbih0 = (const float*)d_in[26];
  const float* sbhh0 = (const float*)d_in[27];
  const float* sWih1 = (const float*)d_in[28];
  const float* sWhh1 = (const float*)d_in[29];
  const float* sbih1 = (const float*)d_in[30];
  const float* sbhh1 = (const float*)d_in[31];
  const float* spW   = (const float*)d_in[32];
  const float* spb   = (const float*)d_in[33];
  const float* pa    = (const float*)d_in[34];
  float* out = (float*)d_out;
  float* ws = (float*)d_ws;

  float* x0    = ws + OFF_X0;
  float* hA    = ws + OFF_HA;
  float* hB    = ws + OFF_HB;
  float* ef    = ws + OFF_EF;
  float* amsg0 = ws + OFF_AMSG0;
  float* amsg1 = ws + OFF_AMSG1;
  float* nacc0 = ws + OFF_NACC0;
  float* nacc1 = ws + OFF_NACC1;
  float* agg   = ws + OFF_AGG;
  float* qstar = ws + OFF_QSTAR;
  float* h0a = ws + OFF_H0A; float* h0b = ws + OFF_H0B;
  float* c0a = ws + OFF_C0A; float* c0b = ws + OFF_C0B;
  float* h1a = ws + OFF_H1A; float* h1b = ws + OFF_H1B;
  float* c1a = ws + OFF_C1A; float* c1b = ws + OFF_C1B;
  int* gstart  = (int*)(ws + OFF_GSTART);
  float* wang = ws + OFF_WANG;
  h16* ttA  = (h16*)(ws + OFF_TT_ANG);
  h16* ttB  = (h16*)(ws + OFF_TT_BOND);
  h16* wtAU = (h16*)(ws + OFF_WT_AU);
  h16* wtBU = (h16*)(ws + OFF_WT_BU);
  h16* w3t  = (h16*)(ws + OFF_W3T);
  h16* P8   = (h16*)(ws + OFF_P8);
  float* Q    = ws + OFF_Q;

  hipMemsetAsync(gstart, 0x7f, 2 * N_B * sizeof(int), stream);
  k_setup<<<SB_END, 256, 0, stream>>>(
      na, projW, projb, ea, el, ang, gid, gWih, gWhh, efW, efb, bondW, bondb,
      auW, buW, x0, ef, wang, gstart, gstart + N_B, w3t, ttA, ttB, wtAU, wtBU,
      (float4*)amsg0, (float4*)nacc0, (float4*)qstar);

  const int EGX = (N_E + 127) / 128;
  const float* cur = x0;
  float* bufs[2] = {hA, hB};
  float* amsgs[2] = {amsg0, amsg1};
  float* naccs[2] = {nacc0, nacc1};
  for (int s = 0; s < 4; ++s) {
    float* amsg_c = amsgs[s & 1];
    float* amsg_o = amsgs[(s + 1) & 1];
    float* nacc_c = naccs[s & 1];
    float* nacc_o = naccs[(s + 1) & 1];
    k_edgeP<<<dim3(EGX, 4), 256, 0, stream>>>(cur, esrc, wtAU, aub, ttA, ef, P8, Q);
    k_angle<<<(N_A * 64) / 256, 256, 0, stream>>>(wang, asrc, adst, P8, Q, amsg_c);
    k_bond<<<dim3(EGX, 4), 256, 0, stream>>>(cur, esrc, wtBU, bub, amsg_c, ef, ttB,
                                             edst, nacc_c, (float4*)amsg_o,
                                             N_E * 64 / 4);
    float* nxt = bufs[s & 1];
    k_gru2<<<(N_N + 31) / 32, 128, 0, stream>>>(nacc_c, gnnb, cur, w3t, gbih, gbhh,
                                                nxt, x0, agg, (s == 3) ? 1 : 0,
                                                (float4*)nacc_o, N_N * 64 / 4);
    cur = nxt;
  }

  // ---- Set2Set (qstar/h/c zeroed by k_setup) ----
  float *h0i = h0a, *h0o = h0b, *c0i = c0a, *c0o = c0b;
  float *h1i = h1a, *h1o = h1b, *c1i = c1a, *c1o = c1b;
  for (int it = 0; it < 3; ++it) {
    k_lstm2<<<(N_B * 128 * 64 + 255) / 256, 256, 0, stream>>>(
        qstar, 256, h0i, c0i, sWih0, sWhh0, sbih0, sbhh0, h0o, c0o);
    k_lstm2<<<(N_B * 128 * 64 + 255) / 256, 256, 0, stream>>>(
        h0o, 128, h1i, c1i, sWih1, sWhh1, sbih1, sbhh1, h1o, c1o);
    k_pool2<<<N_B, 256, 0, stream>>>(agg, gstart, gstart + N_B, h1o, qstar);
    float* tmp;
    tmp = h0i; h0i = h0o; h0o = tmp;
    tmp = c0i; c0i = c0o; c0o = tmp;
    tmp = h1i; h1i = h1o; h1o = tmp;
    tmp = c1i; c1i = c1o; c1o = tmp;
  }
  k_out<<<(N_B * N_DH + 255) / 256, 256, 0, stream>>>(qstar, spW, spb, pa, out);
}